// Round 2
// baseline (190.981 us; speedup 1.0000x reference)
//
#include <hip/hip_runtime.h>

typedef unsigned short u16;
typedef __attribute__((ext_vector_type(8))) short bf16x8;   // 8 bf16 = 4 VGPRs
typedef __attribute__((ext_vector_type(4))) float f32x4;    // MFMA 16x16 accumulator

__device__ __forceinline__ u16 f2b(float f) {
    unsigned u = __builtin_bit_cast(unsigned, f);
    return (u16)((u + 0x7FFFu + ((u >> 16) & 1u)) >> 16);   // RNE fp32->bf16
}

// ---------------------------------------------------------------------------
// Prep: build bf16 MFMA B-fragments for qkv_w (24 ntiles x 4 ksteps) and
// proj_w (8 x 4), fragment f stored at ushort offset f*512, lane-major:
// elem(l,i) at f*512 + l*8 + i holds W[k = ks*32 + (l>>4)*8 + i][col = nt*16 + (l&15)].
// Also expand bias table to dense [4][16][16] fp32 at float offset 32768.
// ---------------------------------------------------------------------------
__global__ void prep_kernel(const float* __restrict__ qkv_w,
                            const float* __restrict__ proj_w,
                            const float* __restrict__ bias_tbl,
                            u16* __restrict__ wsb, float* __restrict__ wsf)
{
    int tid = blockIdx.x * 256 + threadIdx.x;
    if (tid < 49152) {                      // qkv_w fragments
        int i = tid & 7, l = (tid >> 3) & 63, f = tid >> 9;
        int nt = f >> 2, ks = f & 3;
        int k = ks * 32 + (l >> 4) * 8 + i;
        int col = nt * 16 + (l & 15);
        wsb[tid] = f2b(qkv_w[k * 384 + col]);
    } else if (tid < 65536) {               // proj_w fragments
        int e = tid - 49152;
        int i = e & 7, l = (e >> 3) & 63, f = e >> 9;
        int nt = f >> 2, ks = f & 3;
        int k = ks * 32 + (l >> 4) * 8 + i;
        int col = nt * 16 + (l & 15);
        wsb[tid] = f2b(proj_w[k * 128 + col]);
    } else if (tid < 66560) {               // bias expand: [h][t1][t2]
        int e = tid - 65536;
        int h = e >> 8, t1 = (e >> 4) & 15, t2 = e & 15;
        int idx = ((t1 >> 2) - (t2 >> 2) + 3) * 7 + ((t1 & 3) - (t2 & 3) + 3);
        wsf[32768 + e] = bias_tbl[idx * 4 + h];
    }
}

// ---------------------------------------------------------------------------
// Fused window attention: one 64-thread wave per window.
// LDS (ushort units):
//   [0    .. 4224)  q|k staging, [16 tok][264]  (row stride 528 B, 16B-aligned)
//   [4224 .. 7296)  vT,          [128 ch][24]   (row stride 48 B; cols 16..23 pad)
//   [7296 .. 8832)  P per head,  4 x [16][24]
//   AO reuses region 0 with stride 136 (272 B rows).
// ---------------------------------------------------------------------------
__global__ __launch_bounds__(64) void winattn_kernel(
    const float* __restrict__ x, const u16* __restrict__ wfrag,
    const float* __restrict__ qkv_b, const float* __restrict__ proj_b,
    const float* __restrict__ biasx, float* __restrict__ out)
{
    __shared__ alignas(16) u16 lds[8832];
    const int lane = threadIdx.x;
    const int g = lane >> 4, q16 = lane & 15;
    const int wid = blockIdx.x;
    const int b = wid >> 10, rem = wid & 1023, wi = rem >> 5, wj = rem & 31;

    // Zero the vT padding columns (tokens 16..23 of each channel row): the PV
    // B-fragment reads them (A-side is zero there, but 0*NaN = NaN if LDS
    // holds garbage). 128 rows x 8 ushorts, 2 x ds_write_b128 per lane.
    {
        bf16x8 z = {0, 0, 0, 0, 0, 0, 0, 0};
        *(bf16x8*)&lds[4224 + (2 * lane + 0) * 24 + 16] = z;
        *(bf16x8*)&lds[4224 + (2 * lane + 1) * 24 + 16] = z;
    }

    // this lane's token row (token index q16): n = (wi*4 + r)*128 + wj*4 + c
    const int nTok = (wi * 4 + (q16 >> 2)) * 128 + wj * 4 + (q16 & 3);
    const float* xrow = x + ((long)b * 16384 + nTok) * 128;

    // ---- x A-fragments: lane holds x[token q16][ch = ks*32 + g*8 + i] ----
    bf16x8 ax[4];
    #pragma unroll
    for (int ks = 0; ks < 4; ++ks) {
        const float4* p = (const float4*)(xrow + ks * 32 + g * 8);
        float4 v0 = p[0], v1 = p[1];
        bf16x8 a;
        a[0] = (short)f2b(v0.x); a[1] = (short)f2b(v0.y);
        a[2] = (short)f2b(v0.z); a[3] = (short)f2b(v0.w);
        a[4] = (short)f2b(v1.x); a[5] = (short)f2b(v1.y);
        a[6] = (short)f2b(v1.z); a[7] = (short)f2b(v1.w);
        ax[ks] = a;
    }

    const bf16x8* wv = (const bf16x8*)wfrag;

    // ---- qkv projection: 24 tiles x 4 k-steps ----
    #pragma unroll 2
    for (int nt = 0; nt < 24; ++nt) {
        int col = nt * 16 + q16;
        float b0 = qkv_b[col];
        f32x4 acc = {b0, b0, b0, b0};
        #pragma unroll
        for (int ks = 0; ks < 4; ++ks) {
            bf16x8 bf = wv[(nt * 4 + ks) * 64 + lane];
            acc = __builtin_amdgcn_mfma_f32_16x16x32_bf16(ax[ks], bf, acc, 0, 0, 0);
        }
        // D-frag: row(token) = 4g+r, col = nt*16 + q16
        if (nt < 16) {          // q (cols 0..127), k (cols 128..255)
            #pragma unroll
            for (int r = 0; r < 4; ++r) lds[(4 * g + r) * 264 + col] = f2b(acc[r]);
        } else {                // v: store transposed vT[ch][token]
            int c2 = col - 256;
            #pragma unroll
            for (int r = 0; r < 4; ++r) lds[4224 + c2 * 24 + 4 * g + r] = f2b(acc[r]);
        }
    }
    __syncthreads();

    // ---- attention ----
    const float scale = 0.17677669529663689f;   // 32^-0.5
    f32x4 oacc[8];
    f32x4 z4 = {0.f, 0.f, 0.f, 0.f};
    #pragma unroll
    for (int j = 0; j < 8; ++j) oacc[j] = z4;

    #pragma unroll 1
    for (int h = 0; h < 4; ++h) {
        // Q A-frag: Q[tok q16][d = g*8+i];  K B-frag: K[key q16][d = g*8+i]
        bf16x8 qf = *(const bf16x8*)&lds[q16 * 264 + h * 32 + g * 8];
        bf16x8 kf = *(const bf16x8*)&lds[q16 * 264 + 128 + h * 32 + g * 8];
        f32x4 s = __builtin_amdgcn_mfma_f32_16x16x32_bf16(qf, kf, z4, 0, 0, 0);
        // S[query=4g+r][key=q16]; softmax across the 16 lanes of each group
        #pragma unroll
        for (int r = 0; r < 4; ++r) {
            float sv = s[r] * scale + biasx[(h * 16 + 4 * g + r) * 16 + q16];
            float m = sv;
            m = fmaxf(m, __shfl_xor(m, 1));
            m = fmaxf(m, __shfl_xor(m, 2));
            m = fmaxf(m, __shfl_xor(m, 4));
            m = fmaxf(m, __shfl_xor(m, 8));
            float e = __expf(sv - m);
            float su = e;
            su += __shfl_xor(su, 1);
            su += __shfl_xor(su, 2);
            su += __shfl_xor(su, 4);
            su += __shfl_xor(su, 8);
            lds[7296 + h * 384 + (4 * g + r) * 24 + q16] = f2b(e / su);
        }
    }
    __syncthreads();

    #pragma unroll 1
    for (int h = 0; h < 4; ++h) {
        // P A-frag: P[query q16][key = g*8+i], keys 16..31 are zero padding
        bf16x8 pf = {0, 0, 0, 0, 0, 0, 0, 0};
        if (g < 2) pf = *(const bf16x8*)&lds[7296 + h * 384 + q16 * 24 + g * 8];
        #pragma unroll
        for (int dt = 0; dt < 2; ++dt) {
            // V B-frag: V[key = g*8+i][d = dt*16 + q16] from vT
            bf16x8 vf = *(const bf16x8*)&lds[4224 + (h * 32 + dt * 16 + q16) * 24 + g * 8];
            oacc[h * 2 + dt] =
                __builtin_amdgcn_mfma_f32_16x16x32_bf16(pf, vf, oacc[h * 2 + dt], 0, 0, 0);
        }
    }
    __syncthreads();

    // ---- stage attention output (bf16) for proj A-frags ----
    #pragma unroll
    for (int h = 0; h < 4; ++h)
        #pragma unroll
        for (int dt = 0; dt < 2; ++dt)
            #pragma unroll
            for (int r = 0; r < 4; ++r)
                lds[(4 * g + r) * 136 + h * 32 + dt * 16 + q16] = f2b(oacc[h * 2 + dt][r]);
    __syncthreads();

    bf16x8 af[4];
    #pragma unroll
    for (int ks = 0; ks < 4; ++ks)
        af[ks] = *(const bf16x8*)&lds[q16 * 136 + ks * 32 + g * 8];

    // ---- proj: 8 tiles x 4 k-steps, fp32 store ----
    #pragma unroll 2
    for (int nt = 0; nt < 8; ++nt) {
        int col = nt * 16 + q16;
        float p0 = proj_b[col];
        f32x4 acc = {p0, p0, p0, p0};
        #pragma unroll
        for (int ks = 0; ks < 4; ++ks) {
            bf16x8 bf = wv[(96 + nt * 4 + ks) * 64 + lane];
            acc = __builtin_amdgcn_mfma_f32_16x16x32_bf16(af[ks], bf, acc, 0, 0, 0);
        }
        #pragma unroll
        for (int r = 0; r < 4; ++r) {
            int t = 4 * g + r;
            int n = (wi * 4 + (t >> 2)) * 128 + wj * 4 + (t & 3);
            out[((long)b * 16384 + n) * 128 + col] = acc[r];
        }
    }
}

extern "C" void kernel_launch(void* const* d_in, const int* in_sizes, int n_in,
                              void* d_out, int out_size, void* d_ws, size_t ws_size,
                              hipStream_t stream)
{
    const float* x        = (const float*)d_in[0];
    const float* qkv_w    = (const float*)d_in[3];
    const float* qkv_b    = (const float*)d_in[4];
    const float* proj_w   = (const float*)d_in[5];
    const float* proj_b   = (const float*)d_in[6];
    const float* bias_tbl = (const float*)d_in[7];

    u16*   wsb = (u16*)d_ws;
    float* wsf = (float*)d_ws;

    prep_kernel<<<260, 256, 0, stream>>>(qkv_w, proj_w, bias_tbl, wsb, wsf);
    winattn_kernel<<<16384, 64, 0, stream>>>(x, wsb, qkv_b, proj_b,
                                             wsf + 32768, (float*)d_out);
}

// Round 4
// 144.425 us; speedup vs baseline: 1.3224x; 1.3224x over previous
//
#include <hip/hip_runtime.h>

typedef unsigned short u16;
typedef unsigned int   u32;
typedef __attribute__((ext_vector_type(8))) short bf16x8;   // 8 bf16 = 4 VGPRs
typedef __attribute__((ext_vector_type(4))) float f32x4;    // MFMA 16x16 accumulator

union F8 { bf16x8 v; u32 u[4]; };

__device__ __forceinline__ u16 f2b(float f) {
    unsigned u = __builtin_bit_cast(unsigned, f);
    return (u16)((u + 0x7FFFu + ((u >> 16) & 1u)) >> 16);   // RNE fp32->bf16
}
__device__ __forceinline__ u32 pkbf(float a, float b) {     // pack 2 bf16
    return ((u32)f2b(b) << 16) | (u32)f2b(a);
}

// ---------------------------------------------------------------------------
// Prep: bf16 MFMA weight fragments. Fragment f at ushort f*512,
// elem(l,i) = W[k = ks*32 + (l>>4)*8 + i][col = nt*16 + (l&15)].
// Used as A-operand of the transposed GEMMs (A-frag of W^T == B-frag of W).
// Bias table expanded to [h][query][key] fp32 at float offset 32768.
// ---------------------------------------------------------------------------
__global__ void prep_kernel(const float* __restrict__ qkv_w,
                            const float* __restrict__ proj_w,
                            const float* __restrict__ bias_tbl,
                            u16* __restrict__ wsb, float* __restrict__ wsf)
{
    int tid = blockIdx.x * 256 + threadIdx.x;
    if (tid < 49152) {                      // qkv_w fragments
        int i = tid & 7, l = (tid >> 3) & 63, f = tid >> 9;
        int nt = f >> 2, ks = f & 3;
        int k = ks * 32 + (l >> 4) * 8 + i;
        int col = nt * 16 + (l & 15);
        wsb[tid] = f2b(qkv_w[k * 384 + col]);
    } else if (tid < 65536) {               // proj_w fragments
        int e = tid - 49152;
        int i = e & 7, l = (e >> 3) & 63, f = e >> 9;
        int nt = f >> 2, ks = f & 3;
        int k = ks * 32 + (l >> 4) * 8 + i;
        int col = nt * 16 + (l & 15);
        wsb[tid] = f2b(proj_w[k * 128 + col]);
    } else if (tid < 66560) {               // bias expand: [h][t1=query][t2=key]
        int e = tid - 65536;
        int h = e >> 8, t1 = (e >> 4) & 15, t2 = e & 15;
        int idx = ((t1 >> 2) - (t2 >> 2) + 3) * 7 + ((t1 & 3) - (t2 & 3) + 3);
        wsf[32768 + e] = bias_tbl[idx * 4 + h];
    }
}

// ---------------------------------------------------------------------------
// Fused window attention, transposed-GEMM form. 4 waves/block, 1 window/wave.
// Only LDS: per-wave vT [d 0..127][tok 0..15 + 8 pad], stride 24 u16 (48 B).
// All other inter-stage transposes are packed-bf16 __shfl exchanges.
// ---------------------------------------------------------------------------
__global__ __launch_bounds__(256) void winattn_kernel(
    const float* __restrict__ x, const u16* __restrict__ wfrag,
    const float* __restrict__ qkv_b, const float* __restrict__ proj_b,
    const float* __restrict__ biasx, float* __restrict__ out)
{
    __shared__ alignas(16) u16 lds[4][3104];
    const int tid  = threadIdx.x;
    const int wave = tid >> 6, lane = tid & 63;
    const int g = lane >> 4, q16 = lane & 15;
    u16* vT = lds[wave];

    const int wid = blockIdx.x * 4 + wave;
    const int b = wid >> 10, rem = wid & 1023, wi = rem >> 5, wj = rem & 31;

    // zero vT pad (cols 16..23 each row + row-127 overflow) — PV B-side is 0
    // for keys>=16 but 0*garbage(NaN) = NaN, so A-side pad must be finite.
    {
        bf16x8 z = {0, 0, 0, 0, 0, 0, 0, 0};
        *(bf16x8*)&vT[(2 * lane + 0) * 24 + 16] = z;
        *(bf16x8*)&vT[(2 * lane + 1) * 24 + 16] = z;
        if (lane == 0) *(bf16x8*)&vT[3072] = z;
    }

    // lane's token row (token = q16)
    const int nTok = (wi * 4 + (q16 >> 2)) * 128 + wj * 4 + (q16 & 3);
    const float* xrow = x + ((long)b * 16384 + nTok) * 128;

    // x^T B-fragments: lane holds x[tok q16][ch = ks*32 + g*8 + i]
    F8 ax[4];
    #pragma unroll
    for (int ks = 0; ks < 4; ++ks) {
        const float4* p = (const float4*)(xrow + ks * 32 + g * 8);
        float4 v0 = p[0], v1 = p[1];
        ax[ks].u[0] = pkbf(v0.x, v0.y); ax[ks].u[1] = pkbf(v0.z, v0.w);
        ax[ks].u[2] = pkbf(v1.x, v1.y); ax[ks].u[3] = pkbf(v1.z, v1.w);
    }

    const bf16x8* wv = (const bf16x8*)wfrag;

    // ---- qkv^T GEMM: D[col nt*16+4g+r][tok q16] = (W^T x^T + b) ----
    u32 Qpk[8][2], Kpk[8][2];
    #pragma unroll
    for (int nt = 0; nt < 8; ++nt) {        // Q tiles (cols 0..127)
        float4 bb = *(const float4*)&qkv_b[nt * 16 + 4 * g];
        f32x4 acc = {bb.x, bb.y, bb.z, bb.w};
        #pragma unroll
        for (int ks = 0; ks < 4; ++ks)
            acc = __builtin_amdgcn_mfma_f32_16x16x32_bf16(wv[(nt * 4 + ks) * 64 + lane],
                                                          ax[ks].v, acc, 0, 0, 0);
        Qpk[nt][0] = pkbf(acc[0], acc[1]);
        Qpk[nt][1] = pkbf(acc[2], acc[3]);
    }
    #pragma unroll
    for (int nt = 8; nt < 16; ++nt) {       // K tiles (cols 128..255)
        float4 bb = *(const float4*)&qkv_b[nt * 16 + 4 * g];
        f32x4 acc = {bb.x, bb.y, bb.z, bb.w};
        #pragma unroll
        for (int ks = 0; ks < 4; ++ks)
            acc = __builtin_amdgcn_mfma_f32_16x16x32_bf16(wv[(nt * 4 + ks) * 64 + lane],
                                                          ax[ks].v, acc, 0, 0, 0);
        Kpk[nt - 8][0] = pkbf(acc[0], acc[1]);
        Kpk[nt - 8][1] = pkbf(acc[2], acc[3]);
    }
    #pragma unroll 2
    for (int nt = 16; nt < 24; ++nt) {      // V tiles -> vT LDS (d rows)
        float4 bb = *(const float4*)&qkv_b[nt * 16 + 4 * g];
        f32x4 acc = {bb.x, bb.y, bb.z, bb.w};
        #pragma unroll
        for (int ks = 0; ks < 4; ++ks)
            acc = __builtin_amdgcn_mfma_f32_16x16x32_bf16(wv[(nt * 4 + ks) * 64 + lane],
                                                          ax[ks].v, acc, 0, 0, 0);
        int dbase = (nt - 16) * 16 + 4 * g;
        #pragma unroll
        for (int r = 0; r < 4; ++r) vT[(dbase + r) * 24 + q16] = f2b(acc[r]);
    }
    __syncthreads();

    // ---- attention (all in registers except vT reads) ----
    const float scale = 0.17677669529663689f;   // 32^-0.5
    const int s0  = (2 * (g & 1)) * 16 + q16;   // shfl src lanes for frag build
    const int s1  = s0 + 16;
    const int sel = g >> 1;

    f32x4 oacc[8];
    f32x4 z4 = {0.f, 0.f, 0.f, 0.f};
    #pragma unroll
    for (int j = 0; j < 8; ++j) oacc[j] = z4;

    #pragma unroll
    for (int h = 0; h < 4; ++h) {
        // build qf/kf: [tok/key q16][d g*8+i] from packed D-frags
        F8 qf, kf;
        #pragma unroll
        for (int j = 0; j < 4; ++j) {
            int src = (j < 2) ? s0 : s1;
            u32 qlo = (u32)__shfl((int)Qpk[2 * h][j & 1], src, 64);
            u32 qhi = (u32)__shfl((int)Qpk[2 * h + 1][j & 1], src, 64);
            qf.u[j] = sel ? qhi : qlo;
            u32 klo = (u32)__shfl((int)Kpk[2 * h][j & 1], src, 64);
            u32 khi = (u32)__shfl((int)Kpk[2 * h + 1][j & 1], src, 64);
            kf.u[j] = sel ? khi : klo;
        }
        // S^T tile: lane holds S[q=q16][key=4g+r]
        f32x4 s = __builtin_amdgcn_mfma_f32_16x16x32_bf16(kf.v, qf.v, z4, 0, 0, 0);
        float4 bias4 = *(const float4*)&biasx[(h * 16 + q16) * 16 + 4 * g];
        float sv0 = s[0] * scale + bias4.x;
        float sv1 = s[1] * scale + bias4.y;
        float sv2 = s[2] * scale + bias4.z;
        float sv3 = s[3] * scale + bias4.w;
        float m = fmaxf(fmaxf(sv0, sv1), fmaxf(sv2, sv3));
        m = fmaxf(m, __shfl_xor(m, 16, 64));
        m = fmaxf(m, __shfl_xor(m, 32, 64));
        float e0 = __expf(sv0 - m), e1 = __expf(sv1 - m);
        float e2 = __expf(sv2 - m), e3 = __expf(sv3 - m);
        float su = e0 + e1 + e2 + e3;
        su += __shfl_xor(su, 16, 64);
        su += __shfl_xor(su, 32, 64);
        float rs = 1.0f / su;
        u32 pk0 = pkbf(e0 * rs, e1 * rs), pk1 = pkbf(e2 * rs, e3 * rs);
        // P B-frag: [key g*8+i][tok q16]; keys >=16 are zero
        F8 pf;
        int t0 = ((2 * g) * 16 + q16) & 63, t1 = (t0 + 16) & 63;
        pf.u[0] = (u32)__shfl((int)pk0, t0, 64);
        pf.u[1] = (u32)__shfl((int)pk1, t0, 64);
        pf.u[2] = (u32)__shfl((int)pk0, t1, 64);
        pf.u[3] = (u32)__shfl((int)pk1, t1, 64);
        if (g >= 2) { pf.u[0] = 0; pf.u[1] = 0; pf.u[2] = 0; pf.u[3] = 0; }
        // O^T = V^T P^T: lane gets O[tok q16][d = h*32+dt*16+4g+r]
        #pragma unroll
        for (int dt = 0; dt < 2; ++dt) {
            bf16x8 vf = *(const bf16x8*)&vT[(h * 32 + dt * 16 + q16) * 24 + g * 8];
            oacc[h * 2 + dt] =
                __builtin_amdgcn_mfma_f32_16x16x32_bf16(vf, pf.v, oacc[h * 2 + dt], 0, 0, 0);
        }
    }

    // pack AO, build proj B-frags af: [ch ks*32+g*8+i][tok q16]
    u32 Opk[4][2][2];
    #pragma unroll
    for (int h = 0; h < 4; ++h)
        #pragma unroll
        for (int dt = 0; dt < 2; ++dt) {
            Opk[h][dt][0] = pkbf(oacc[h * 2 + dt][0], oacc[h * 2 + dt][1]);
            Opk[h][dt][1] = pkbf(oacc[h * 2 + dt][2], oacc[h * 2 + dt][3]);
        }
    F8 af[4];
    #pragma unroll
    for (int ks = 0; ks < 4; ++ks)
        #pragma unroll
        for (int j = 0; j < 4; ++j) {
            int src = (j < 2) ? s0 : s1;
            u32 lo = (u32)__shfl((int)Opk[ks][0][j & 1], src, 64);
            u32 hi = (u32)__shfl((int)Opk[ks][1][j & 1], src, 64);
            af[ks].u[j] = sel ? hi : lo;
        }

    // ---- proj^T GEMM + store: lane writes float4 runs of its token row ----
    const long obase = ((long)b * 16384 + nTok) * 128;
    #pragma unroll 2
    for (int nt = 0; nt < 8; ++nt) {
        float4 bb = *(const float4*)&proj_b[nt * 16 + 4 * g];
        f32x4 acc = {bb.x, bb.y, bb.z, bb.w};
        #pragma unroll
        for (int ks = 0; ks < 4; ++ks)
            acc = __builtin_amdgcn_mfma_f32_16x16x32_bf16(wv[(96 + nt * 4 + ks) * 64 + lane],
                                                          af[ks].v, acc, 0, 0, 0);
        float4 o; o.x = acc[0]; o.y = acc[1]; o.z = acc[2]; o.w = acc[3];
        *(float4*)&out[obase + nt * 16 + 4 * g] = o;
    }
}

extern "C" void kernel_launch(void* const* d_in, const int* in_sizes, int n_in,
                              void* d_out, int out_size, void* d_ws, size_t ws_size,
                              hipStream_t stream)
{
    const float* x        = (const float*)d_in[0];
    const float* qkv_w    = (const float*)d_in[3];
    const float* qkv_b    = (const float*)d_in[4];
    const float* proj_w   = (const float*)d_in[5];
    const float* proj_b   = (const float*)d_in[6];
    const float* bias_tbl = (const float*)d_in[7];

    u16*   wsb = (u16*)d_ws;
    float* wsf = (float*)d_ws;

    prep_kernel<<<260, 256, 0, stream>>>(qkv_w, proj_w, bias_tbl, wsb, wsf);
    winattn_kernel<<<4096, 256, 0, stream>>>(x, wsb, qkv_b, proj_b,
                                             wsf + 32768, (float*)d_out);
}